// Round 2
// baseline (3958.834 us; speedup 1.0000x reference)
//
#include <hip/hip_runtime.h>
#include <hip/hip_bf16.h>

typedef long long i64;

__device__ __forceinline__ float sigf(float x){ return 1.f/(1.f + __expf(-x)); }

// ---------------- f32 copy ----------------
__global__ void f_copy(const float* __restrict__ in, float* __restrict__ out, long n){
  long i = (long)blockIdx.x*blockDim.x + threadIdx.x;
  if (i < n) out[i] = in[i];
}

// ---------------- LayerNorm over rows (no affine) ----------------
__global__ __launch_bounds__(256) void ln_rows(const float* __restrict__ x,
                                               float* __restrict__ y, int D){
  long base = (long)blockIdx.x * D;
  int t = threadIdx.x;
  float s = 0.f, ss = 0.f;
  for (int i = t; i < D; i += 256){ float v = x[base+i]; s += v; ss += v*v; }
  __shared__ float r0[256], r1[256];
  r0[t] = s; r1[t] = ss; __syncthreads();
  for (int off = 128; off > 0; off >>= 1){
    if (t < off){ r0[t] += r0[t+off]; r1[t] += r1[t+off]; }
    __syncthreads();
  }
  float mean = r0[0]/D;
  float var  = r1[0]/D - mean*mean;
  float rstd = rsqrtf(var + 1e-5f);
  for (int i = t; i < D; i += 256) y[base+i] = (x[base+i]-mean)*rstd;
}

// ---------------- per-column scale (apply LN weight) ----------------
__global__ void scale_cols(const float* __restrict__ x, const float* __restrict__ w,
                           float* __restrict__ y, int D, long n){
  long i = (long)blockIdx.x*256 + threadIdx.x;
  if (i < n) y[i] = x[i] * w[i % D];
}

// ---------------- a2 = sigmoid(P1*AN + P2), in place over P2 ----------------
__global__ void adaln_combine(const float* __restrict__ P1, const float* __restrict__ AN,
                              float* __restrict__ P2, long n){
  long i = (long)blockIdx.x*256 + threadIdx.x;
  if (i < n){ float v = P1[i]*AN[i] + P2[i]; P2[i] = sigf(v); }
}

// ---------------- Zp = (ln(z)*pw+pb) @ bwT + bb  -> scores buffer ----------------
// 64 (i,j) positions per block; out[p*16 + m]; flat buffer reinterpreted as (H,S,S) later
__global__ __launch_bounds__(256) void zln_kernel(const float* __restrict__ z,
    const float* __restrict__ pw, const float* __restrict__ pb,
    const float* __restrict__ bw, const float* __restrict__ bbias,
    float* __restrict__ out){
  __shared__ float tile[64][65];
  __shared__ float wpw[64], wpb[64], wbb[16];
  __shared__ float wbw[16][65];
  __shared__ float mean_s[64], rstd_s[64];
  int t = threadIdx.x;
  long p0 = (long)blockIdx.x * 64;
  const float* z2 = z + p0*64;
  for (int i = t; i < 4096; i += 256) tile[i>>6][i&63] = z2[i];
  if (t < 64){ wpw[t] = pw[t]; wpb[t] = pb[t]; }
  if (t < 16) wbb[t] = bbias[t];
  for (int i = t; i < 1024; i += 256) wbw[i>>6][i&63] = bw[i];
  __syncthreads();
  if (t < 64){
    float s = 0.f, ss = 0.f;
    for (int c = 0; c < 64; c++){ float v = tile[t][c]; s += v; ss += v*v; }
    float m = s*(1.f/64.f);
    float var = ss*(1.f/64.f) - m*m;
    mean_s[t] = m; rstd_s[t] = rsqrtf(var + 1e-5f);
  }
  __syncthreads();
  for (int o = t; o < 1024; o += 256){
    int p = o >> 4, mm = o & 15;
    float m = mean_s[p], r = rstd_s[p];
    float dot = 0.f;
    for (int c = 0; c < 64; c++){
      float lnv = (tile[p][c]-m)*r*wpw[c] + wpb[c];
      dot += lnv * wbw[mm][c];
    }
    out[(p0+p)*16 + mm] = dot + wbb[mm];
  }
}

// ---------------- row softmax over 1024, in place ----------------
__global__ __launch_bounds__(256) void softmax_rows(float* __restrict__ sc){
  long base = (long)blockIdx.x * 1024;
  float4* row = (float4*)(sc + base);
  int t = threadIdx.x;
  float4 v = row[t];
  float mx = fmaxf(fmaxf(v.x,v.y), fmaxf(v.z,v.w));
  for (int off = 32; off > 0; off >>= 1) mx = fmaxf(mx, __shfl_down(mx, off));
  __shared__ float sm[4], ssum[4];
  int wv = t >> 6, ln = t & 63;
  if (ln == 0) sm[wv] = mx;
  __syncthreads();
  mx = fmaxf(fmaxf(sm[0],sm[1]), fmaxf(sm[2],sm[3]));
  float e0 = __expf(v.x-mx), e1 = __expf(v.y-mx), e2 = __expf(v.z-mx), e3 = __expf(v.w-mx);
  float s = e0+e1+e2+e3;
  for (int off = 32; off > 0; off >>= 1) s += __shfl_down(s, off);
  if (ln == 0) ssum[wv] = s;
  __syncthreads();
  float inv = 1.f/(ssum[0]+ssum[1]+ssum[2]+ssum[3]);
  row[t] = make_float4(e0*inv, e1*inv, e2*inv, e3*inv);
}

// ---------------- bb = silu(h1)*h2 ----------------
__global__ void silu_mul(const float* __restrict__ h, float* __restrict__ bb, long n){
  long i = (long)blockIdx.x*256 + threadIdx.x;
  if (i < n){
    long tt = i/1536, c = i%1536;
    float h1 = h[tt*3072 + c], h2 = h[tt*3072 + 1536 + c];
    bb[i] = h1*sigf(h1)*h2;
  }
}

// ---------------- a_next = sig(gate)*attnmm + sig(sg*trb) ----------------
__global__ void final_combine(const float* __restrict__ attnmm, const float* __restrict__ gate,
                              const float* __restrict__ sg, const float* __restrict__ trb,
                              float* __restrict__ a_cur, float* __restrict__ outp, long n){
  long i = (long)blockIdx.x*256 + threadIdx.x;
  if (i < n){
    float v = sigf(gate[i])*attnmm[i] + sigf(sg[i]*trb[i]);
    a_cur[i] = v;
    if (outp) outp[i] = v;
  }
}

// ---------------- generic strided batched GEMM: C = alpha*A(M,K)·B(N,K)^T (+epi) ----------------
// EPI 0: C = r (+bias[n]);  EPI 1: C += r;  EPI 2: C = sigmoid(aux[m,n])*r
template<int EPI>
__global__ __launch_bounds__(256) void gemm_nt(
    const float* __restrict__ A, i64 rsA, i64 csA, i64 sbA,
    const float* __restrict__ B, i64 rsB, i64 csB, i64 sbB,
    float* __restrict__ C, i64 ldc, i64 sbC,
    const float* __restrict__ bias,
    const float* __restrict__ aux, i64 rsAux, i64 sbAux,
    int M, int Nn, int K, float alpha)
{
  __shared__ float As[16][68];
  __shared__ float Bs[16][68];
  int bz = blockIdx.z;
  A += (i64)bz*sbA; B += (i64)bz*sbB; C += (i64)bz*sbC;
  if (EPI == 2) aux += (i64)bz*sbAux;
  int m0 = blockIdx.y*64, n0 = blockIdx.x*64;
  int t = threadIdx.x;
  int tx = t & 15, ty = t >> 4;
  float acc[4][4] = {};
  for (int k0 = 0; k0 < K; k0 += 16){
    if (csA == 1){
      for (int i = t; i < 1024; i += 256){
        int m = i >> 4, kk = i & 15;
        int gm = m0 + m;
        As[kk][m] = (gm < M) ? A[(i64)gm*rsA + (k0+kk)] : 0.f;
      }
    } else {
      for (int i = t; i < 1024; i += 256){
        int m = i & 63, kk = i >> 6;
        int gm = m0 + m;
        As[kk][m] = (gm < M) ? A[(i64)gm*rsA + (i64)(k0+kk)*csA] : 0.f;
      }
    }
    if (csB == 1){
      for (int i = t; i < 1024; i += 256){
        int n = i >> 4, kk = i & 15;
        int gn = n0 + n;
        Bs[kk][n] = (gn < Nn) ? B[(i64)gn*rsB + (k0+kk)] : 0.f;
      }
    } else {
      for (int i = t; i < 1024; i += 256){
        int n = i & 63, kk = i >> 6;
        int gn = n0 + n;
        Bs[kk][n] = (gn < Nn) ? B[(i64)gn*rsB + (i64)(k0+kk)*csB] : 0.f;
      }
    }
    __syncthreads();
#pragma unroll
    for (int kk = 0; kk < 16; kk++){
      float av[4], bv[4];
#pragma unroll
      for (int i = 0; i < 4; i++) av[i] = As[kk][ty*4+i];
#pragma unroll
      for (int j = 0; j < 4; j++) bv[j] = Bs[kk][tx*4+j];
#pragma unroll
      for (int i = 0; i < 4; i++)
#pragma unroll
        for (int j = 0; j < 4; j++)
          acc[i][j] = fmaf(av[i], bv[j], acc[i][j]);
    }
    __syncthreads();
  }
#pragma unroll
  for (int i = 0; i < 4; i++){
    int gm = m0 + ty*4 + i;
    if (gm >= M) continue;
#pragma unroll
    for (int j = 0; j < 4; j++){
      int gn = n0 + tx*4 + j;
      if (gn >= Nn) continue;
      float r = acc[i][j]*alpha;
      i64 idx = (i64)gm*ldc + gn;
      if (EPI == 0){ if (bias) r += bias[gn]; C[idx] = r; }
      else if (EPI == 1){ C[idx] += r; }
      else { float g = aux[(i64)gm*rsAux + gn]; C[idx] = sigf(g)*r; }
    }
  }
}

extern "C" void kernel_launch(void* const* d_in, const int* in_sizes, int n_in,
                              void* d_out, int out_size, void* d_ws, size_t ws_size,
                              hipStream_t stream){
  const float* a_in   = (const float*)d_in[0];
  const float* s_in   = (const float*)d_in[1];
  const float* z_in   = (const float*)d_in[2];
  const float* attn_sn_w = (const float*)d_in[3];
  const float* attn_pb_w = (const float*)d_in[4];
  const float* attn_pb_b = (const float*)d_in[5];
  const float* attn_pnb_w= (const float*)d_in[6];
  const float* pair_w = (const float*)d_in[7];
  const float* pair_b = (const float*)d_in[8];
  const float* q_w    = (const float*)d_in[9];
  const float* q_b    = (const float*)d_in[10];
  const float* kvg_w  = (const float*)d_in[11];
  const float* bias_w = (const float*)d_in[12];
  const float* bias_b = (const float*)d_in[13];
  const float* ao_w   = (const float*)d_in[14];
  const float* out_w  = (const float*)d_in[15];
  const float* out_b  = (const float*)d_in[16];
  const float* tr_sn_w= (const float*)d_in[17];
  const float* tr_pb_w= (const float*)d_in[18];
  const float* tr_pb_b= (const float*)d_in[19];
  const float* tr_pnb_w=(const float*)d_in[20];
  const float* tr_a_w = (const float*)d_in[21];
  const float* tr_s_w = (const float*)d_in[22];
  const float* tr_s_b = (const float*)d_in[23];
  const float* tr_b_w = (const float*)d_in[24];

  float* ws      = (float*)d_ws;
  float* scores  = ws;                       // 16777216 (H*S*S) — also Zp (flat-identical)
  float* a_cur   = scores + 16777216;        // 786432
  float* s_f     = a_cur + 786432;           // 393216
  float* AN      = s_f + 393216;             // 786432
  float* SN0     = AN + 786432;              // 393216
  float* SNw     = SN0 + 393216;             // 393216
  float* P1      = SNw + 393216;             // 786432
  float* a2      = P1 + 786432;              // 786432 (also a3)
  float* qproj   = a2 + 786432;              // 786432
  float* kvg     = qproj + 786432;           // 2359296
  float* ogated  = kvg + 2359296;            // 786432
  float* attnmm  = ogated + 786432;          // 786432
  float* gatebuf = attnmm + 786432;          // 786432
  float* hbuf    = scores;                   // reuse scores (free after OV), 3145728
  float* bbuf    = scores + 3145728;         // 1572864
  float* trb     = qproj;                    // reuse (free after QK)
  float* sgate   = ogated;                   // reuse (free after ao GEMM)

  f_copy<<<3072,256,0,stream>>>(a_in, a_cur, 786432);
  f_copy<<<1536,256,0,stream>>>(s_in, s_f, 393216);
  ln_rows<<<1024,256,0,stream>>>(s_f, SN0, 384);   // LN(s), layer-independent

  for (int l = 0; l < 2; l++){
    ln_rows<<<1024,256,0,stream>>>(a_cur, AN, 768);

    // ---- AttentionPairBias: adaln ----
    scale_cols<<<1536,256,0,stream>>>(SN0, attn_sn_w + l*384, SNw, 384, 393216);
    gemm_nt<0><<<dim3(12,16,1),256,0,stream>>>(SNw,384,1,0, attn_pb_w + (i64)l*294912,384,1,0,
        P1,768,0, attn_pb_b + l*768, nullptr,0,0, 1024,768,384, 1.f);
    gemm_nt<0><<<dim3(12,16,1),256,0,stream>>>(SNw,384,1,0, attn_pnb_w + (i64)l*294912,384,1,0,
        a2,768,0, nullptr, nullptr,0,0, 1024,768,384, 1.f);
    adaln_combine<<<3072,256,0,stream>>>(P1, AN, a2, 786432);

    // ---- projections ----
    gemm_nt<0><<<dim3(12,16,1),256,0,stream>>>(a2,768,1,0, q_w + (i64)l*589824,768,1,0,
        qproj,768,0, q_b + l*768, nullptr,0,0, 1024,768,768, 1.f);
    gemm_nt<0><<<dim3(36,16,1),256,0,stream>>>(a2,768,1,0, kvg_w + (i64)l*1769472,768,1,0,
        kvg,2304,0, nullptr, nullptr,0,0, 1024,2304,768, 1.f);

    // ---- pair bias: Zp into scores ----
    zln_kernel<<<16384,256,0,stream>>>(z_in, pair_w + l*64, pair_b + l*64,
        bias_w + l*1024, bias_b + l*16, scores);

    // ---- scores[h,x,y] += K[x]·Q[y]/48 (batched over heads) ----
    gemm_nt<1><<<dim3(16,16,16),256,0,stream>>>(kvg,144,1,147456, qproj,48,1,49152,
        scores,1024,1048576, nullptr, nullptr,0,0, 1024,1024,48, 1.f/48.f);
    softmax_rows<<<16384,256,0,stream>>>(scores);

    // ---- o[j,c] = Σ_x A[x,j]·V[x,c], gated by sigmoid(g[j,c]) ----
    gemm_nt<2><<<dim3(1,16,16),256,0,stream>>>(scores,1,1024,1048576, kvg+48,1,144,147456,
        ogated,48,49152, nullptr, kvg+96,144,147456, 1024,48,1024, 1.f);

    gemm_nt<0><<<dim3(12,16,1),256,0,stream>>>(ogated,768,1,0, ao_w + (i64)l*589824,768,1,0,
        attnmm,768,0, nullptr, nullptr,0,0, 1024,768,768, 1.f);
    gemm_nt<0><<<dim3(12,16,1),256,0,stream>>>(s_f,384,1,0, out_w + (i64)l*294912,384,1,0,
        gatebuf,768,0, out_b + l*768, nullptr,0,0, 1024,768,384, 1.f);

    // ---- ConditionedTransitionBlock ----
    scale_cols<<<1536,256,0,stream>>>(SN0, tr_sn_w + l*384, SNw, 384, 393216);
    gemm_nt<0><<<dim3(12,16,1),256,0,stream>>>(SNw,384,1,0, tr_pb_w + (i64)l*294912,384,1,0,
        P1,768,0, tr_pb_b + l*768, nullptr,0,0, 1024,768,384, 1.f);
    gemm_nt<0><<<dim3(12,16,1),256,0,stream>>>(SNw,384,1,0, tr_pnb_w + (i64)l*294912,384,1,0,
        a2,768,0, nullptr, nullptr,0,0, 1024,768,384, 1.f);
    adaln_combine<<<3072,256,0,stream>>>(P1, AN, a2, 786432);

    gemm_nt<0><<<dim3(48,16,1),256,0,stream>>>(a2,768,1,0, tr_a_w + (i64)l*2359296,768,1,0,
        hbuf,3072,0, nullptr, nullptr,0,0, 1024,3072,768, 1.f);
    silu_mul<<<6144,256,0,stream>>>(hbuf, bbuf, 1572864);
    gemm_nt<0><<<dim3(12,16,1),256,0,stream>>>(bbuf,1536,1,0, tr_b_w + (i64)l*1179648,1536,1,0,
        trb,768,0, nullptr, nullptr,0,0, 1024,768,1536, 1.f);
    gemm_nt<0><<<dim3(12,16,1),256,0,stream>>>(s_f,384,1,0, tr_s_w + (i64)l*294912,384,1,0,
        sgate,768,0, tr_s_b + l*768, nullptr,0,0, 1024,768,384, 1.f);

    final_combine<<<3072,256,0,stream>>>(attnmm, gatebuf, sgate, trb, a_cur,
        (l==1) ? (float*)d_out : (float*)nullptr, 786432);
  }
}

// Round 3
// 1441.488 us; speedup vs baseline: 2.7464x; 2.7464x over previous
//
#include <hip/hip_runtime.h>
#include <hip/hip_bf16.h>

typedef long long i64;
typedef unsigned short u16;
typedef __attribute__((ext_vector_type(8))) short short8;
typedef __attribute__((ext_vector_type(4))) float f32x4;

__device__ __forceinline__ float sigf(float x){ return 1.f/(1.f + __expf(-x)); }
__device__ __forceinline__ u16 f2bu(float v){
  union{ __hip_bfloat16 h; u16 u; } cv; cv.h = __float2bfloat16(v); return cv.u;
}

// ---------------- f32 -> bf16 vectorized convert ----------------
__global__ void f2b(const float* __restrict__ in, u16* __restrict__ outp, long n){
  long i = ((long)blockIdx.x*256 + threadIdx.x)*4;
  if (i < n){
    float4 v = *(const float4*)(in + i);
    outp[i]   = f2bu(v.x); outp[i+1] = f2bu(v.y);
    outp[i+2] = f2bu(v.z); outp[i+3] = f2bu(v.w);
  }
}

// ---------------- per-layer weight pool convert (11 arrays, fixed sizes) ----------------
__global__ void f2b_wpool(const float* __restrict__ w0, const float* __restrict__ w1,
                          const float* __restrict__ w2, const float* __restrict__ w3,
                          const float* __restrict__ w4, const float* __restrict__ w5,
                          const float* __restrict__ w6, const float* __restrict__ w7,
                          const float* __restrict__ w8, const float* __restrict__ w9,
                          const float* __restrict__ w10, u16* __restrict__ pool){
  long i = ((long)blockIdx.x*256 + threadIdx.x)*4;
  if (i >= 8257536) return;
  const float* src; long rel;
  if      (i <  294912){ src=w0;  rel=i; }
  else if (i <  589824){ src=w1;  rel=i-294912; }
  else if (i < 1179648){ src=w2;  rel=i-589824; }
  else if (i < 2949120){ src=w3;  rel=i-1179648; }
  else if (i < 3538944){ src=w4;  rel=i-2949120; }
  else if (i < 3833856){ src=w5;  rel=i-3538944; }
  else if (i < 4128768){ src=w6;  rel=i-3833856; }
  else if (i < 4423680){ src=w7;  rel=i-4128768; }
  else if (i < 6782976){ src=w8;  rel=i-4423680; }
  else if (i < 7077888){ src=w9;  rel=i-6782976; }
  else                 { src=w10; rel=i-7077888; }
  float4 v = *(const float4*)(src + rel);
  pool[i]   = f2bu(v.x); pool[i+1] = f2bu(v.y);
  pool[i+2] = f2bu(v.z); pool[i+3] = f2bu(v.w);
}

// ---------------- LayerNorm over rows (no affine) ----------------
__global__ __launch_bounds__(256) void ln_rows(const float* __restrict__ x,
                                               float* __restrict__ y, int D){
  long base = (long)blockIdx.x * D;
  int t = threadIdx.x;
  float s = 0.f, ss = 0.f;
  for (int i = t; i < D; i += 256){ float v = x[base+i]; s += v; ss += v*v; }
  __shared__ float r0[256], r1[256];
  r0[t] = s; r1[t] = ss; __syncthreads();
  for (int off = 128; off > 0; off >>= 1){
    if (t < off){ r0[t] += r0[t+off]; r1[t] += r1[t+off]; }
    __syncthreads();
  }
  float mean = r0[0]/D;
  float var  = r1[0]/D - mean*mean;
  float rstd = rsqrtf(var + 1e-5f);
  for (int i = t; i < D; i += 256) y[base+i] = (x[base+i]-mean)*rstd;
}

// ---------------- y_bf = x * w[col] ----------------
__global__ void scale_cols_bf(const float* __restrict__ x, const float* __restrict__ w,
                              u16* __restrict__ y, int D, long n){
  long i = (long)blockIdx.x*256 + threadIdx.x;
  if (i < n) y[i] = f2bu(x[i] * w[i % D]);
}

// ---------------- a2_bf = sigmoid(P1*AN + P2) ----------------
__global__ void adaln_combine_bf(const float* __restrict__ P1, const float* __restrict__ AN,
                                 const float* __restrict__ P2, u16* __restrict__ outb, long n){
  long i = (long)blockIdx.x*256 + threadIdx.x;
  if (i < n) outb[i] = f2bu(sigf(P1[i]*AN[i] + P2[i]));
}

// ---------------- register-resident zln: Zp = (ln(z)*pw+pb)@bwT + bb ----------------
// one thread per (i,j) position; weights scalar-promoted (uniform loads)
__global__ __launch_bounds__(256) void zln2(const float* __restrict__ z,
    const float* __restrict__ pw, const float* __restrict__ pb,
    const float* __restrict__ bw, const float* __restrict__ bbias,
    float* __restrict__ out){
  i64 p = (i64)blockIdx.x*256 + threadIdx.x;
  const float4* zr = (const float4*)(z + p*64);
  float v[64];
  float s = 0.f, ss = 0.f;
#pragma unroll
  for (int i = 0; i < 16; i++){
    float4 q = zr[i];
    v[4*i] = q.x; v[4*i+1] = q.y; v[4*i+2] = q.z; v[4*i+3] = q.w;
  }
#pragma unroll
  for (int c = 0; c < 64; c++){ s += v[c]; ss = fmaf(v[c], v[c], ss); }
  float m = s*(1.f/64.f);
  float var = ss*(1.f/64.f) - m*m;
  float r = rsqrtf(var + 1e-5f);
#pragma unroll
  for (int c = 0; c < 64; c++) v[c] = (v[c]-m)*r*pw[c] + pb[c];
  float4 o[4];
  float* of = (float*)o;
#pragma unroll
  for (int mm = 0; mm < 16; mm++){
    float acc = bbias[mm];
#pragma unroll
    for (int c = 0; c < 64; c++) acc = fmaf(v[c], bw[mm*64+c], acc);
    of[mm] = acc;
  }
  float4* op = (float4*)(out + p*16);
#pragma unroll
  for (int i = 0; i < 4; i++) op[i] = o[i];
}

// ---------------- row softmax over 1024, in place ----------------
__global__ __launch_bounds__(256) void softmax_rows(float* __restrict__ sc){
  long base = (long)blockIdx.x * 1024;
  float4* row = (float4*)(sc + base);
  int t = threadIdx.x;
  float4 v = row[t];
  float mx = fmaxf(fmaxf(v.x,v.y), fmaxf(v.z,v.w));
  for (int off = 32; off > 0; off >>= 1) mx = fmaxf(mx, __shfl_down(mx, off));
  __shared__ float sm[4], ssum[4];
  int wv = t >> 6, ln = t & 63;
  if (ln == 0) sm[wv] = mx;
  __syncthreads();
  mx = fmaxf(fmaxf(sm[0],sm[1]), fmaxf(sm[2],sm[3]));
  float e0 = __expf(v.x-mx), e1 = __expf(v.y-mx), e2 = __expf(v.z-mx), e3 = __expf(v.w-mx);
  float s = e0+e1+e2+e3;
  for (int off = 32; off > 0; off >>= 1) s += __shfl_down(s, off);
  if (ln == 0) ssum[wv] = s;
  __syncthreads();
  float inv = 1.f/(ssum[0]+ssum[1]+ssum[2]+ssum[3]);
  row[t] = make_float4(e0*inv, e1*inv, e2*inv, e3*inv);
}

// ---------------- bb_bf = silu(h1)*h2 ----------------
__global__ void silu_mul_bf(const float* __restrict__ h, u16* __restrict__ bb, long n){
  long i = (long)blockIdx.x*256 + threadIdx.x;
  if (i < n){
    long tt = i/1536, c = i%1536;
    float h1 = h[tt*3072 + c], h2 = h[tt*3072 + 1536 + c];
    bb[i] = f2bu(h1*sigf(h1)*h2);
  }
}

// ---------------- a_next = sig(gate)*attnmm + sig(sg*trb) ----------------
__global__ void final_combine(const float* __restrict__ attnmm, const float* __restrict__ gate,
                              const float* __restrict__ sg, const float* __restrict__ trb,
                              float* __restrict__ a_cur, float* __restrict__ outp, long n){
  long i = (long)blockIdx.x*256 + threadIdx.x;
  if (i < n){
    float v = sigf(gate[i])*attnmm[i] + sigf(sg[i]*trb[i]);
    a_cur[i] = v;
    if (outp) outp[i] = v;
  }
}

// ---------------- bf16 MFMA GEMM: C(M,N) = A(M,K)·B(N,K)^T, batched/strided ----------------
// EPI 0: r(+bias[n]) -> C (f32, optional) and/or Cbf (bf16 mirror)
// EPI 1: C += alpha*r
template<int EPI>
__global__ __launch_bounds__(256) void gbt(
    const u16* __restrict__ A, i64 lda, i64 sbA,
    const u16* __restrict__ B, i64 ldb, i64 sbB,
    float* __restrict__ C, i64 ldc, i64 sbC,
    u16* __restrict__ Cbf,
    const float* __restrict__ bias,
    int K, float alpha)
{
  __shared__ __align__(16) u16 Asm[64*40];
  __shared__ __align__(16) u16 Bsm[64*40];
  int t = threadIdx.x;
  int bz = blockIdx.z;
  int m0 = blockIdx.y*64, n0 = blockIdx.x*64;
  int srow = t >> 2, skc = (t & 3)*8;
  const u16* Ar = A + (i64)bz*sbA + (i64)(m0+srow)*lda + skc;
  const u16* Br = B + (i64)bz*sbB + (i64)(n0+srow)*ldb + skc;
  int lane = t & 63, wv = t >> 6;
  int la = lane & 15, quad = lane >> 4;
  int moff = (wv >> 1)*32, noff = (wv & 1)*32;
  f32x4 acc[2][2] = {{{0.f,0.f,0.f,0.f},{0.f,0.f,0.f,0.f}},
                     {{0.f,0.f,0.f,0.f},{0.f,0.f,0.f,0.f}}};
  for (int k0 = 0; k0 < K; k0 += 32){
    uint4 av, bv;
    if (k0 + skc < K){
      av = *(const uint4*)(Ar + k0);
      bv = *(const uint4*)(Br + k0);
    } else {
      av = make_uint4(0,0,0,0); bv = av;
    }
    *(uint4*)&Asm[srow*40 + skc] = av;
    *(uint4*)&Bsm[srow*40 + skc] = bv;
    __syncthreads();
    short8 af0 = *(const short8*)&Asm[(moff      + la)*40 + quad*8];
    short8 af1 = *(const short8*)&Asm[(moff + 16 + la)*40 + quad*8];
    short8 bf0 = *(const short8*)&Bsm[(noff      + la)*40 + quad*8];
    short8 bf1 = *(const short8*)&Bsm[(noff + 16 + la)*40 + quad*8];
    acc[0][0] = __builtin_amdgcn_mfma_f32_16x16x32_bf16(af0, bf0, acc[0][0], 0,0,0);
    acc[0][1] = __builtin_amdgcn_mfma_f32_16x16x32_bf16(af0, bf1, acc[0][1], 0,0,0);
    acc[1][0] = __builtin_amdgcn_mfma_f32_16x16x32_bf16(af1, bf0, acc[1][0], 0,0,0);
    acc[1][1] = __builtin_amdgcn_mfma_f32_16x16x32_bf16(af1, bf1, acc[1][1], 0,0,0);
    __syncthreads();
  }
  float* Cb = C ? C + (i64)bz*sbC : nullptr;
  u16* Cb2 = Cbf ? Cbf + (i64)bz*sbC : nullptr;
#pragma unroll
  for (int i = 0; i < 2; i++)
#pragma unroll
   for (int j = 0; j < 2; j++)
#pragma unroll
    for (int r = 0; r < 4; r++){
      int gm = m0 + moff + 16*i + quad*4 + r;
      int gn = n0 + noff + 16*j + la;
      i64 idx = (i64)gm*ldc + gn;
      float v = acc[i][j][r];
      if (EPI == 1){
        Cb[idx] += alpha*v;
      } else {
        if (bias) v += bias[gn];
        if (Cb)  Cb[idx]  = v;
        if (Cb2) Cb2[idx] = f2bu(v);
      }
    }
}

// ---------------- fp32 GEMM (kept for A^T·V attention contraction) ----------------
// EPI 2: C = sigmoid(aux[m,n])*r
template<int EPI>
__global__ __launch_bounds__(256) void gemm_nt(
    const float* __restrict__ A, i64 rsA, i64 csA, i64 sbA,
    const float* __restrict__ B, i64 rsB, i64 csB, i64 sbB,
    float* __restrict__ C, i64 ldc, i64 sbC,
    const float* __restrict__ bias,
    const float* __restrict__ aux, i64 rsAux, i64 sbAux,
    int M, int Nn, int K, float alpha)
{
  __shared__ float As[16][68];
  __shared__ float Bs[16][68];
  int bz = blockIdx.z;
  A += (i64)bz*sbA; B += (i64)bz*sbB; C += (i64)bz*sbC;
  if (EPI == 2) aux += (i64)bz*sbAux;
  int m0 = blockIdx.y*64, n0 = blockIdx.x*64;
  int t = threadIdx.x;
  int tx = t & 15, ty = t >> 4;
  float acc[4][4] = {};
  for (int k0 = 0; k0 < K; k0 += 16){
    if (csA == 1){
      for (int i = t; i < 1024; i += 256){
        int mm = i >> 4, kk = i & 15;
        int gm = m0 + mm;
        As[kk][mm] = (gm < M) ? A[(i64)gm*rsA + (k0+kk)] : 0.f;
      }
    } else {
      for (int i = t; i < 1024; i += 256){
        int mm = i & 63, kk = i >> 6;
        int gm = m0 + mm;
        As[kk][mm] = (gm < M) ? A[(i64)gm*rsA + (i64)(k0+kk)*csA] : 0.f;
      }
    }
    if (csB == 1){
      for (int i = t; i < 1024; i += 256){
        int nn = i >> 4, kk = i & 15;
        int gn = n0 + nn;
        Bs[kk][nn] = (gn < Nn) ? B[(i64)gn*rsB + (k0+kk)] : 0.f;
      }
    } else {
      for (int i = t; i < 1024; i += 256){
        int nn = i & 63, kk = i >> 6;
        int gn = n0 + nn;
        Bs[kk][nn] = (gn < Nn) ? B[(i64)gn*rsB + (i64)(k0+kk)*csB] : 0.f;
      }
    }
    __syncthreads();
#pragma unroll
    for (int kk = 0; kk < 16; kk++){
      float av[4], bv[4];
#pragma unroll
      for (int i = 0; i < 4; i++) av[i] = As[kk][ty*4+i];
#pragma unroll
      for (int j = 0; j < 4; j++) bv[j] = Bs[kk][tx*4+j];
#pragma unroll
      for (int i = 0; i < 4; i++)
#pragma unroll
        for (int j = 0; j < 4; j++)
          acc[i][j] = fmaf(av[i], bv[j], acc[i][j]);
    }
    __syncthreads();
  }
#pragma unroll
  for (int i = 0; i < 4; i++){
    int gm = m0 + ty*4 + i;
    if (gm >= M) continue;
#pragma unroll
    for (int j = 0; j < 4; j++){
      int gn = n0 + tx*4 + j;
      if (gn >= Nn) continue;
      float r = acc[i][j]*alpha;
      i64 idx = (i64)gm*ldc + gn;
      if (EPI == 2){ float g = aux[(i64)gm*rsAux + gn]; C[idx] = sigf(g)*r; }
      else { if (bias) r += bias[gn]; C[idx] = r; }
    }
  }
}

extern "C" void kernel_launch(void* const* d_in, const int* in_sizes, int n_in,
                              void* d_out, int out_size, void* d_ws, size_t ws_size,
                              hipStream_t stream){
  const float* a_in   = (const float*)d_in[0];
  const float* s_in   = (const float*)d_in[1];
  const float* z_in   = (const float*)d_in[2];
  const float* attn_sn_w = (const float*)d_in[3];
  const float* attn_pb_w = (const float*)d_in[4];
  const float* attn_pb_b = (const float*)d_in[5];
  const float* attn_pnb_w= (const float*)d_in[6];
  const float* pair_w = (const float*)d_in[7];
  const float* pair_b = (const float*)d_in[8];
  const float* q_w    = (const float*)d_in[9];
  const float* q_b    = (const float*)d_in[10];
  const float* kvg_w  = (const float*)d_in[11];
  const float* bias_w = (const float*)d_in[12];
  const float* bias_b = (const float*)d_in[13];
  const float* ao_w   = (const float*)d_in[14];
  const float* out_w  = (const float*)d_in[15];
  const float* out_b  = (const float*)d_in[16];
  const float* tr_sn_w= (const float*)d_in[17];
  const float* tr_pb_w= (const float*)d_in[18];
  const float* tr_pb_b= (const float*)d_in[19];
  const float* tr_pnb_w=(const float*)d_in[20];
  const float* tr_a_w = (const float*)d_in[21];
  const float* tr_s_w = (const float*)d_in[22];
  const float* tr_s_b = (const float*)d_in[23];
  const float* tr_b_w = (const float*)d_in[24];

  // -------- workspace layout --------
  float* ws      = (float*)d_ws;
  float* scores  = ws;                     // 16777216 f32 (H,S,S); also Zp, hbuf/trb/sgate reuse
  float* hbuf    = scores;                 // 3145728 (after AV consumed scores)
  float* trb     = scores + 3145728;       // 786432
  float* sgate   = scores + 3932160;       // 786432
  float* a_cur   = ws + 16777216;          // 786432
  float* AN      = a_cur + 786432;         // 786432
  float* SN0     = AN + 786432;            // 393216
  float* P1      = SN0 + 393216;           // 786432
  float* P2      = P1 + 786432;            // 786432
  float* kvg     = P2 + 786432;            // 2359296
  float* ogated  = kvg + 2359296;          // 786432
  float* attnmm  = ogated + 786432;        // 786432
  float* gatebuf = attnmm + 786432;        // 786432
  u16* wpool     = (u16*)(gatebuf + 786432);   // 8257536 bf16 (per-layer weights)
  u16* SNw_bf    = wpool + 8257536;        // 393216
  u16* s_bf      = SNw_bf + 393216;        // 393216
  u16* a2bf      = s_bf + 393216;          // 786432
  u16* qproj_bf  = a2bf + 786432;          // 786432
  u16* kvg_bf    = qproj_bf + 786432;      // 2359296
  u16* ogated_bf = kvg_bf + 2359296;       // 786432
  u16* bbuf_bf   = ogated_bf + 786432;     // 1572864
  // total ~130.8 MB

  // pool offsets (bf16 elems)
  const i64 OFF_PB=0, OFF_PNB=294912, OFF_Q=589824, OFF_KVG=1179648, OFF_AO=2949120,
            OFF_OUT=3538944, OFF_TPB=3833856, OFF_TPNB=4128768, OFF_TRA=4423680,
            OFF_TRS=6782976, OFF_TRB=7077888;

  f2b<<<384,256,0,stream>>>(s_in, s_bf, 393216);
  ln_rows<<<1024,256,0,stream>>>(s_in, SN0, 384);   // LN(s), layer-independent

  for (int l = 0; l < 2; l++){
    f2b_wpool<<<8064,256,0,stream>>>(
        attn_pb_w + (i64)l*294912, attn_pnb_w + (i64)l*294912,
        q_w + (i64)l*589824, kvg_w + (i64)l*1769472, ao_w + (i64)l*589824,
        out_w + (i64)l*294912, tr_pb_w + (i64)l*294912, tr_pnb_w + (i64)l*294912,
        tr_a_w + (i64)l*2359296, tr_s_w + (i64)l*294912, tr_b_w + (i64)l*1179648, wpool);

    ln_rows<<<1024,256,0,stream>>>(l == 0 ? a_in : a_cur, AN, 768);

    // ---- AttentionPairBias: adaln ----
    scale_cols_bf<<<1536,256,0,stream>>>(SN0, attn_sn_w + l*384, SNw_bf, 384, 393216);
    gbt<0><<<dim3(12,16,1),256,0,stream>>>(SNw_bf,384,0, wpool+OFF_PB,384,0,
        P1,768,0, nullptr, attn_pb_b + l*768, 384, 1.f);
    gbt<0><<<dim3(12,16,1),256,0,stream>>>(SNw_bf,384,0, wpool+OFF_PNB,384,0,
        P2,768,0, nullptr, nullptr, 384, 1.f);
    adaln_combine_bf<<<3072,256,0,stream>>>(P1, AN, P2, a2bf, 786432);

    // ---- projections (bf16 MFMA) ----
    gbt<0><<<dim3(12,16,1),256,0,stream>>>(a2bf,768,0, wpool+OFF_Q,768,0,
        nullptr,768,0, qproj_bf, q_b + l*768, 768, 1.f);
    gbt<0><<<dim3(36,16,1),256,0,stream>>>(a2bf,768,0, wpool+OFF_KVG,768,0,
        kvg,2304,0, kvg_bf, nullptr, 768, 1.f);

    // ---- pair bias: Zp into scores (flat identity with bmat) ----
    zln2<<<4096,256,0,stream>>>(z_in, pair_w + l*64, pair_b + l*64,
        bias_w + l*1024, bias_b + l*16, scores);

    // ---- scores[h,x,y] += K[x]·Q[y]/48 (MFMA, batched over heads) ----
    gbt<1><<<dim3(16,16,16),256,0,stream>>>(kvg_bf,144,147456, qproj_bf,48,49152,
        scores,1024,1048576, nullptr, nullptr, 48, 1.f/48.f);
    softmax_rows<<<16384,256,0,stream>>>(scores);

    // ---- o[j,c] = Σ_x A[x,j]·V[x,c], gated by sigmoid(g[j,c]) (fp32) ----
    gemm_nt<2><<<dim3(1,16,16),256,0,stream>>>(scores,1,1024,1048576, kvg+48,1,144,147456,
        ogated,48,49152, nullptr, kvg+96,144,147456, 1024,48,1024, 1.f);
    f2b<<<768,256,0,stream>>>(ogated, ogated_bf, 786432);

    gbt<0><<<dim3(12,16,1),256,0,stream>>>(ogated_bf,768,0, wpool+OFF_AO,768,0,
        attnmm,768,0, nullptr, nullptr, 768, 1.f);
    gbt<0><<<dim3(12,16,1),256,0,stream>>>(s_bf,384,0, wpool+OFF_OUT,384,0,
        gatebuf,768,0, nullptr, out_b + l*768, 384, 1.f);

    // ---- ConditionedTransitionBlock ----
    scale_cols_bf<<<1536,256,0,stream>>>(SN0, tr_sn_w + l*384, SNw_bf, 384, 393216);
    gbt<0><<<dim3(12,16,1),256,0,stream>>>(SNw_bf,384,0, wpool+OFF_TPB,384,0,
        P1,768,0, nullptr, tr_pb_b + l*768, 384, 1.f);
    gbt<0><<<dim3(12,16,1),256,0,stream>>>(SNw_bf,384,0, wpool+OFF_TPNB,384,0,
        P2,768,0, nullptr, nullptr, 384, 1.f);
    adaln_combine_bf<<<3072,256,0,stream>>>(P1, AN, P2, a2bf, 786432);

    gbt<0><<<dim3(48,16,1),256,0,stream>>>(a2bf,768,0, wpool+OFF_TRA,768,0,
        hbuf,3072,0, nullptr, nullptr, 768, 1.f);
    silu_mul_bf<<<6144,256,0,stream>>>(hbuf, bbuf_bf, 1572864);
    gbt<0><<<dim3(12,16,1),256,0,stream>>>(bbuf_bf,1536,0, wpool+OFF_TRB,1536,0,
        trb,768,0, nullptr, nullptr, 1536, 1.f);
    gbt<0><<<dim3(12,16,1),256,0,stream>>>(s_bf,384,0, wpool+OFF_TRS,384,0,
        sgate,768,0, nullptr, tr_s_b + l*768, 384, 1.f);

    final_combine<<<3072,256,0,stream>>>(attnmm, gatebuf, sgate, trb, a_cur,
        (l==1) ? (float*)d_out : (float*)nullptr, 786432);
  }
}